// Round 5
// baseline (144.265 us; speedup 1.0000x reference)
//
#include <hip/hip_runtime.h>
#include <hip/hip_bf16.h>

#define B_    8
#define H_    8
#define L_    1024
#define D_    32
#define C_    256
#define NK    64

typedef __attribute__((ext_vector_type(8))) short bf16x8;
typedef __attribute__((ext_vector_type(4))) float f32x4;

__device__ inline unsigned short f2bf(float f) {
    union { float f; unsigned int u; } x; x.f = f;
    return (unsigned short)((x.u + 0x7fffu + ((x.u >> 16) & 1u)) >> 16);
}

__device__ inline unsigned int pk_bf16(float lo, float hi) {
    union { __hip_bfloat162 h; unsigned int u; } c;
    c.h = __float22bfloat162_rn(make_float2(lo, hi));
    return c.u;
}

// ---------------------------------------------------------------------------
// Prep: write K and V in MFMA-FRAGMENT order so the main kernel's fragment
// loads are single coalesced dwordx4 global loads (no LDS staging at all).
//   kfrag[((bh*16+c)*4 + nt)*64 + lane]*8 : lane(quad,l16) = K[c*64+nt*16+l16][quad*8+j]
//   vfrag[(bh*16+c)*2048 + s2*1024 + nt*512 + lane*8] :
//       lane(quad,l16) = V[c*64+s2*32+quad*8+j][nt*16+l16]   (B-frag of PV)
// grid 1024 = (bh 64) x (chunk 16), 256 threads.
// ---------------------------------------------------------------------------
__global__ __launch_bounds__(256) void prep_frag(
    const float* __restrict__ k, const float* __restrict__ v,
    unsigned short* __restrict__ kfrag, unsigned short* __restrict__ vfrag)
{
    const int tid = threadIdx.x;
    const int blk = blockIdx.x;
    const int bh = blk >> 4, c = blk & 15;
    const int b = bh >> 3, h = bh & 7;

    __shared__ float sKf[64 * 36];   // stride 36: 16B-aligned rows
    __shared__ float sVf[64 * 33];   // stride 33: conflict-free column reads

    {   // coalesced load of the 64x32 K and V tiles
        const int row = tid >> 2, seg = tid & 3;
        const size_t src = (size_t)(b * L_ + c * 64 + row) * C_ + h * D_ + seg * 8;
        float4 a = *(const float4*)(k + src);
        float4 d = *(const float4*)(k + src + 4);
        *(float4*)(sKf + row * 36 + seg * 8) = a;
        *(float4*)(sKf + row * 36 + seg * 8 + 4) = d;
        float4 va = *(const float4*)(v + src);
        float4 vd = *(const float4*)(v + src + 4);
        float* vr = sVf + row * 33 + seg * 8;
        vr[0] = va.x; vr[1] = va.y; vr[2] = va.z; vr[3] = va.w;
        vr[4] = vd.x; vr[5] = vd.y; vr[6] = vd.z; vr[7] = vd.w;
    }
    __syncthreads();

    const int ln = tid & 63, u = tid >> 6;
    const int l16 = ln & 15, quad = ln >> 4;

    {   // K fragment, nt = u
        const float* src = sKf + (u * 16 + l16) * 36 + quad * 8;
        float4 a = *(const float4*)src;
        float4 d = *(const float4*)(src + 4);
        uint4 o = { pk_bf16(a.x, a.y), pk_bf16(a.z, a.w),
                    pk_bf16(d.x, d.y), pk_bf16(d.z, d.w) };
        *(uint4*)(kfrag + (size_t)blk * 2048 + u * 512 + ln * 8) = o;
    }
    {   // V fragment, s2 = u>>1, nt = u&1
        const int s2 = u >> 1, nt = u & 1;
        float vals[8];
#pragma unroll
        for (int j = 0; j < 8; ++j)
            vals[j] = sVf[(s2 * 32 + quad * 8 + j) * 33 + nt * 16 + l16];
        uint4 o = { pk_bf16(vals[0], vals[1]), pk_bf16(vals[2], vals[3]),
                    pk_bf16(vals[4], vals[5]), pk_bf16(vals[6], vals[7]) };
        *(uint4*)(vfrag + (size_t)blk * 2048 + s2 * 1024 + nt * 512 + ln * 8) = o;
    }
}

// ---------------------------------------------------------------------------
// Main: 256 thr = 4 waves, 64 q-rows/block, grid 1024, head-XCD swizzle.
// NO barriers in the K-loop. K/V fragments: direct coalesced global loads
// (L1/L2). Only LDS: wave-local S round-trip (C-layout write -> row-major
// read) + mask row. Bias: 4 contiguous dwordx4 per chunk per lane.
// Row sums: extra MFMA vs constant ones B-frag -> lsum lands in C-layout regs.
// ---------------------------------------------------------------------------
__global__ __launch_bounds__(256, 4) void attn_fa(
    const float* __restrict__ q,
    const float* __restrict__ v,
    const int*   __restrict__ mask,
    const float* __restrict__ bias,
    const unsigned short* __restrict__ kfrag,
    const unsigned short* __restrict__ vfrag,
    float*       __restrict__ out)
{
    __shared__ float sMadd[L_];          // 4 KB
    __shared__ float sS[4][16 * 68];     // 17.4 KB, wave-local S tiles

    const int tid  = threadIdx.x;
    const int wv   = tid >> 6;
    const int ln   = tid & 63;
    const int l16  = ln & 15;
    const int quad = ln >> 4;

    const int blk = blockIdx.x;
    const int h   = blk >> 7;            // stride-128 head swizzle: 8 heads of a
    const int rem = blk & 127;           // (b,qt) share an XCD -> bias L2 reuse
    const int b   = rem >> 4;
    const int qt  = rem & 15;
    const int q0  = qt * 64 + wv * 16;
    const int bh  = b * H_ + h;

    const float scale = 0.17677669529663687f; // 1/sqrt(32), folded into Q

    {   // mask -> additive floats (whole batch row, staged once)
        int4 m = ((const int4*)(mask + b * L_))[tid];
        sMadd[tid * 4 + 0] = m.x ? 0.f : -1e9f;
        sMadd[tid * 4 + 1] = m.y ? 0.f : -1e9f;
        sMadd[tid * 4 + 2] = m.z ? 0.f : -1e9f;
        sMadd[tid * 4 + 3] = m.w ? 0.f : -1e9f;
    }
    __syncthreads();

    bf16x8 qfrag;   // A-frag of Q * scale
    {
        const float* qp = q + ((size_t)(b * L_ + q0 + l16) * C_ + h * D_ + quad * 8);
        float4 a = ((const float4*)qp)[0];
        float4 c = ((const float4*)qp)[1];
        __align__(16) unsigned int u[4] = {
            pk_bf16(a.x * scale, a.y * scale), pk_bf16(a.z * scale, a.w * scale),
            pk_bf16(c.x * scale, c.y * scale), pk_bf16(c.z * scale, c.w * scale)};
        qfrag = *(const bf16x8*)u;
    }

    bf16x8 onesf;
#pragma unroll
    for (int i = 0; i < 8; ++i) onesf[i] = (short)0x3F80;   // bf16 1.0

    const unsigned short* kf_base = kfrag + (size_t)bh * 32768 + ln * 8;
    const unsigned short* vf_base = vfrag + (size_t)bh * 32768 + ln * 8;
    const float* bias_row = bias + (size_t)(b * L_ + q0 + l16) * L_;
    float* const sSw   = &sS[wv][0];
    const float* sSrow = &sS[wv][0] + l16 * 68;

    f32x4 Oacc[2] = {{0.f,0.f,0.f,0.f},{0.f,0.f,0.f,0.f}};
    f32x4 Lacc    = {0.f,0.f,0.f,0.f};

    for (int c = 0; c < 16; ++c) {
        const int j0 = c * NK;

        // ---- QK^T: fragment loads straight from global (coalesced 1KB/wave) ----
        const unsigned short* kp = kf_base + c * 2048;
        bf16x8 kf0 = *(const bf16x8*)(kp);
        bf16x8 kf1 = *(const bf16x8*)(kp + 512);
        bf16x8 kf2 = *(const bf16x8*)(kp + 1024);
        bf16x8 kf3 = *(const bf16x8*)(kp + 1536);

        f32x4 S[4];
        S[0] = __builtin_amdgcn_mfma_f32_16x16x32_bf16(qfrag, kf0, (f32x4){0.f,0.f,0.f,0.f}, 0, 0, 0);
        S[1] = __builtin_amdgcn_mfma_f32_16x16x32_bf16(qfrag, kf1, (f32x4){0.f,0.f,0.f,0.f}, 0, 0, 0);
        S[2] = __builtin_amdgcn_mfma_f32_16x16x32_bf16(qfrag, kf2, (f32x4){0.f,0.f,0.f,0.f}, 0, 0, 0);
        S[3] = __builtin_amdgcn_mfma_f32_16x16x32_bf16(qfrag, kf3, (f32x4){0.f,0.f,0.f,0.f}, 0, 0, 0);

        // ---- C-layout scatter to LDS (wave-local; DS in-order per wave) ----
#pragma unroll
        for (int nt = 0; nt < 4; ++nt)
#pragma unroll
            for (int r = 0; r < 4; ++r)
                sSw[(quad * 4 + r) * 68 + nt * 16 + l16] = S[nt][r];

        // ---- row-major read-back + bias + mask + exp -> P frags (in regs) ----
        bf16x8 pf[2];
#pragma unroll
        for (int s2 = 0; s2 < 2; ++s2) {
            const float* sr = sSrow + s2 * 32 + quad * 8;
            float4 a0 = *(const float4*)(sr);
            float4 a1 = *(const float4*)(sr + 4);
            const float* bp = bias_row + j0 + s2 * 32 + quad * 8;
            float4 b0 = *(const float4*)(bp);
            float4 b1 = *(const float4*)(bp + 4);
            const float* mp = sMadd + j0 + s2 * 32 + quad * 8;
            float4 m0 = *(const float4*)(mp);
            float4 m1 = *(const float4*)(mp + 4);
            float p0 = __expf(a0.x + b0.x + m0.x);
            float p1 = __expf(a0.y + b0.y + m0.y);
            float p2 = __expf(a0.z + b0.z + m0.z);
            float p3 = __expf(a0.w + b0.w + m0.w);
            float p4 = __expf(a1.x + b1.x + m1.x);
            float p5 = __expf(a1.y + b1.y + m1.y);
            float p6 = __expf(a1.z + b1.z + m1.z);
            float p7 = __expf(a1.w + b1.w + m1.w);
            __align__(16) unsigned int u[4] = {
                pk_bf16(p0, p1), pk_bf16(p2, p3),
                pk_bf16(p4, p5), pk_bf16(p6, p7)};
            pf[s2] = *(const bf16x8*)u;
        }

        // ---- PV + row-sum via ones-frag MFMA ----
        const unsigned short* vp = vf_base + c * 2048;
#pragma unroll
        for (int s2 = 0; s2 < 2; ++s2) {
            Lacc = __builtin_amdgcn_mfma_f32_16x16x32_bf16(pf[s2], onesf, Lacc, 0, 0, 0);
#pragma unroll
            for (int nt = 0; nt < 2; ++nt) {
                bf16x8 vfr = *(const bf16x8*)(vp + s2 * 1024 + nt * 512);
                Oacc[nt] = __builtin_amdgcn_mfma_f32_16x16x32_bf16(pf[s2], vfr, Oacc[nt], 0, 0, 0);
            }
        }
    }

    // ---- epilogue: Lacc holds row-sums in C-layout; no shuffles needed ----
#pragma unroll
    for (int r = 0; r < 4; ++r) {
        const int qrow = q0 + quad * 4 + r;
        const float inv = 1.f / Lacc[r];
        const bool active = (sMadd[qrow] == 0.f);
        const size_t base = (size_t)(b * L_ + qrow) * C_ + h * D_;
#pragma unroll
        for (int nt = 0; nt < 2; ++nt) {
            const size_t idx = base + nt * 16 + l16;
            out[idx] = active ? Oacc[nt][r] * inv : v[idx];
        }
    }
}

// ---------------------------------------------------------------------------
// Round-2 fallback if ws_size < 8 MB (proven correct, self-contained).
// ---------------------------------------------------------------------------
#define MQ    64
#define KSTR  48
#define VSTR  72

__global__ __launch_bounds__(256) void masked_attn_mfma(
    const float* __restrict__ q,
    const float* __restrict__ k,
    const float* __restrict__ v,
    const int*   __restrict__ mask,
    const float* __restrict__ bias,
    float*       __restrict__ out)
{
    __shared__ __align__(16) unsigned short sQ[MQ][KSTR];
    __shared__ __align__(16) unsigned short sKt[NK][KSTR];
    __shared__ __align__(16) unsigned short sVt[D_][VSTR];
    __shared__ __align__(16) unsigned short sP2[4][16][VSTR];
    __shared__ float sMadd2[NK];

    const int tid  = threadIdx.x;
    const int wv   = tid >> 6;
    const int ln   = tid & 63;
    const int l16  = ln & 15;
    const int quad = ln >> 4;

    const int blk = blockIdx.x;
    const int h   = blk & 7;
    const int qt  = (blk >> 3) & 15;
    const int b   = blk >> 7;
    const int q0  = qt * MQ;
    const float scale = 0.17677669529663687f;

    {
        const int row = tid >> 2, d0 = (tid & 3) * 8;
        const float* src = q + ((size_t)(b * L_ + q0 + row) * C_ + h * D_ + d0);
        float4 a = ((const float4*)src)[0];
        float4 c = ((const float4*)src)[1];
        __align__(16) unsigned short t8[8] = {
            f2bf(a.x), f2bf(a.y), f2bf(a.z), f2bf(a.w),
            f2bf(c.x), f2bf(c.y), f2bf(c.z), f2bf(c.w)};
        *(int4*)&sQ[row][d0] = *(const int4*)t8;
    }
    __syncthreads();

    const bf16x8 qfrag = *(const bf16x8*)&sQ[wv * 16 + l16][quad * 8];
    f32x4 Oacc[2] = {{0.f,0.f,0.f,0.f},{0.f,0.f,0.f,0.f}};
    float lsum[4] = {0.f, 0.f, 0.f, 0.f};

    for (int j0 = 0; j0 < L_; j0 += NK) {
        __syncthreads();
        {
            const int row = tid >> 2, d0 = (tid & 3) * 8;
            const size_t src = (size_t)(b * L_ + j0 + row) * C_ + h * D_ + d0;
            float4 ka = ((const float4*)(k + src))[0];
            float4 kb = ((const float4*)(k + src))[1];
            __align__(16) unsigned short t8[8] = {
                f2bf(ka.x), f2bf(ka.y), f2bf(ka.z), f2bf(ka.w),
                f2bf(kb.x), f2bf(kb.y), f2bf(kb.z), f2bf(kb.w)};
            *(int4*)&sKt[row][d0] = *(const int4*)t8;

            float4 va = ((const float4*)(v + src))[0];
            float4 vb = ((const float4*)(v + src))[1];
            sVt[d0 + 0][row] = f2bf(va.x);
            sVt[d0 + 1][row] = f2bf(va.y);
            sVt[d0 + 2][row] = f2bf(va.z);
            sVt[d0 + 3][row] = f2bf(va.w);
            sVt[d0 + 4][row] = f2bf(vb.x);
            sVt[d0 + 5][row] = f2bf(vb.y);
            sVt[d0 + 6][row] = f2bf(vb.z);
            sVt[d0 + 7][row] = f2bf(vb.w);
            if (tid < NK) sMadd2[tid] = mask[b * L_ + j0 + tid] ? 0.f : -1e9f;
        }
        __syncthreads();

        bf16x8 kf[4];
#pragma unroll
        for (int nt = 0; nt < 4; ++nt)
            kf[nt] = *(const bf16x8*)&sKt[nt * 16 + l16][quad * 8];

        f32x4 S[4];
#pragma unroll
        for (int nt = 0; nt < 4; ++nt)
            S[nt] = __builtin_amdgcn_mfma_f32_16x16x32_bf16(
                qfrag, kf[nt], (f32x4){0.f,0.f,0.f,0.f}, 0, 0, 0);

        float psum[4] = {0.f, 0.f, 0.f, 0.f};
        const size_t brow0 = (size_t)(b * L_ + q0 + wv * 16 + quad * 4) * L_ + j0;
#pragma unroll
        for (int nt = 0; nt < 4; ++nt) {
            const float madd = sMadd2[nt * 16 + l16];
#pragma unroll
            for (int r = 0; r < 4; ++r) {
                float s = S[nt][r] * scale + bias[brow0 + (size_t)r * L_ + nt * 16 + l16] + madd;
                float p = __expf(s);
                psum[r] += p;
                S[nt][r] = p;
            }
        }
#pragma unroll
        for (int nt = 0; nt < 4; ++nt)
#pragma unroll
            for (int r = 0; r < 4; ++r)
                sP2[wv][quad * 4 + r][nt * 16 + l16] = f2bf(S[nt][r]);
#pragma unroll
        for (int r = 0; r < 4; ++r) {
            float t = psum[r];
            t += __shfl_xor(t, 1);
            t += __shfl_xor(t, 2);
            t += __shfl_xor(t, 4);
            t += __shfl_xor(t, 8);
            lsum[r] += t;
        }
#pragma unroll
        for (int s2 = 0; s2 < 2; ++s2) {
            bf16x8 pf = *(const bf16x8*)&sP2[wv][l16][s2 * 32 + quad * 8];
#pragma unroll
            for (int nt = 0; nt < 2; ++nt) {
                bf16x8 vf = *(const bf16x8*)&sVt[nt * 16 + l16][s2 * 32 + quad * 8];
                Oacc[nt] = __builtin_amdgcn_mfma_f32_16x16x32_bf16(pf, vf, Oacc[nt], 0, 0, 0);
            }
        }
    }
#pragma unroll
    for (int r = 0; r < 4; ++r) {
        const int qg = q0 + wv * 16 + quad * 4 + r;
        const int active = mask[b * L_ + qg];
        const size_t obase = (size_t)(b * L_ + qg) * C_ + h * D_;
        const float inv = 1.f / lsum[r];
#pragma unroll
        for (int nt = 0; nt < 2; ++nt) {
            float val;
            if (active) val = Oacc[nt][r] * inv;
            else        val = v[obase + nt * 16 + l16];
            out[obase + nt * 16 + l16] = val;
        }
    }
}

extern "C" void kernel_launch(void* const* d_in, const int* in_sizes, int n_in,
                              void* d_out, int out_size, void* d_ws, size_t ws_size,
                              hipStream_t stream) {
    const float* q    = (const float*)d_in[0];
    const float* k    = (const float*)d_in[1];
    const float* v    = (const float*)d_in[2];
    const int*   mask = (const int*)d_in[3];
    const float* bias = (const float*)d_in[4];
    float* out = (float*)d_out;

    if (ws_size >= (size_t)8 * 1024 * 1024) {
        unsigned short* kfrag = (unsigned short*)d_ws;
        unsigned short* vfrag = kfrag + (size_t)2 * 1024 * 1024;  // 4 MB in
        prep_frag<<<1024, 256, 0, stream>>>(k, v, kfrag, vfrag);
        attn_fa<<<1024, 256, 0, stream>>>(q, v, mask, bias, kfrag, vfrag, out);
    } else {
        masked_attn_mfma<<<1024, 256, 0, stream>>>(q, k, v, mask, bias, out);
    }
}

// Round 6
// 127.290 us; speedup vs baseline: 1.1334x; 1.1334x over previous
//
#include <hip/hip_runtime.h>
#include <hip/hip_bf16.h>

#define B_    8
#define H_    8
#define L_    1024
#define D_    32
#define C_    256
#define NK    64
#define PSTR  72

typedef __attribute__((ext_vector_type(8))) short bf16x8;
typedef __attribute__((ext_vector_type(4))) float f32x4;

__device__ inline unsigned short f2bf(float f) {
    union { float f; unsigned int u; } x; x.f = f;
    return (unsigned short)((x.u + 0x7fffu + ((x.u >> 16) & 1u)) >> 16);
}

__device__ inline unsigned int pk_bf16(float lo, float hi) {
    union { __hip_bfloat162 h; unsigned int u; } c;
    c.h = __float22bfloat162_rn(make_float2(lo, hi));
    return c.u;
}

// ---------------------------------------------------------------------------
// Unified prep.
// blocks 0..1023   : K/V -> bf16 MFMA-fragment order (proven rounds 4/5).
//   kfrag[(bh*16+c)*2048 + nt*512 + ln*8]  = K[c*64+nt*16+l16][quad*8+j]
//   vfrag[(bh*16+c)*2048 + s2*1024 + nt*512 + ln*8] = V[c*64+s2*32+quad*8+j][nt*16+l16]
// blocks 1024..1535: bias f32 -> bf16 C-layout frags, KEY-MASK FOLDED IN.
//   bfrag[((b*64+strip)*16+c)*1024 + h*512 + ln*8 + (nt&1)*4 + r]
//       = bf16( bias[b][strip*16+quad*4+r][c*64+nt*16+l16] + (mask?0:-1e9) ),  nt = 2h+(idx>>2)
// ---------------------------------------------------------------------------
__global__ __launch_bounds__(256) void prep_all(
    const float* __restrict__ k, const float* __restrict__ v,
    const float* __restrict__ bias, const int* __restrict__ mask,
    unsigned short* __restrict__ kfrag, unsigned short* __restrict__ vfrag,
    unsigned short* __restrict__ bfrag)
{
    const int tid = threadIdx.x;
    const int blk = blockIdx.x;
    __shared__ float sKf[64 * 36];
    __shared__ float sVf[64 * 33];
    __shared__ float sMadd[L_];

    if (blk < 1024) {
        const int bh = blk >> 4, c = blk & 15;
        const int b = bh >> 3, h = bh & 7;
        {
            const int row = tid >> 2, seg = tid & 3;
            const size_t src = (size_t)(b * L_ + c * 64 + row) * C_ + h * D_ + seg * 8;
            float4 a = *(const float4*)(k + src);
            float4 d = *(const float4*)(k + src + 4);
            *(float4*)(sKf + row * 36 + seg * 8) = a;
            *(float4*)(sKf + row * 36 + seg * 8 + 4) = d;
            float4 va = *(const float4*)(v + src);
            float4 vd = *(const float4*)(v + src + 4);
            float* vr = sVf + row * 33 + seg * 8;
            vr[0] = va.x; vr[1] = va.y; vr[2] = va.z; vr[3] = va.w;
            vr[4] = vd.x; vr[5] = vd.y; vr[6] = vd.z; vr[7] = vd.w;
        }
        __syncthreads();
        const int ln = tid & 63, u = tid >> 6;
        const int l16 = ln & 15, quad = ln >> 4;
        {
            const float* src = sKf + (u * 16 + l16) * 36 + quad * 8;
            float4 a = *(const float4*)src;
            float4 d = *(const float4*)(src + 4);
            uint4 o = { pk_bf16(a.x, a.y), pk_bf16(a.z, a.w),
                        pk_bf16(d.x, d.y), pk_bf16(d.z, d.w) };
            *(uint4*)(kfrag + (size_t)blk * 2048 + u * 512 + ln * 8) = o;
        }
        {
            const int s2 = u >> 1, nt = u & 1;
            float vals[8];
#pragma unroll
            for (int j = 0; j < 8; ++j)
                vals[j] = sVf[(s2 * 32 + quad * 8 + j) * 33 + nt * 16 + l16];
            uint4 o = { pk_bf16(vals[0], vals[1]), pk_bf16(vals[2], vals[3]),
                        pk_bf16(vals[4], vals[5]), pk_bf16(vals[6], vals[7]) };
            *(uint4*)(vfrag + (size_t)blk * 2048 + s2 * 1024 + nt * 512 + ln * 8) = o;
        }
    } else {
        const int bblk = blk - 1024;            // 512 blocks: (b, strip)
        const int b = bblk >> 6, strip = bblk & 63;
        const int wv = tid >> 6, ln = tid & 63;
        const int l16 = ln & 15, quad = ln >> 4;
        {
            int4 m = ((const int4*)(mask + b * L_))[tid];
            sMadd[tid * 4 + 0] = m.x ? 0.f : -1e9f;
            sMadd[tid * 4 + 1] = m.y ? 0.f : -1e9f;
            sMadd[tid * 4 + 2] = m.z ? 0.f : -1e9f;
            sMadd[tid * 4 + 3] = m.w ? 0.f : -1e9f;
        }
        __syncthreads();
        const float* brow = bias + ((size_t)(b * L_) + strip * 16 + quad * 4) * L_;
        unsigned short* obase = bfrag + (size_t)bblk * 16384;
#pragma unroll
        for (int cc = 0; cc < 4; ++cc) {
            const int c = wv * 4 + cc;
            float vals[16];
#pragma unroll
            for (int nt = 0; nt < 4; ++nt) {
                const int col = c * 64 + nt * 16 + l16;
                const float madd = sMadd[col];
#pragma unroll
                for (int r = 0; r < 4; ++r)
                    vals[nt * 4 + r] = brow[(size_t)r * L_ + col] + madd;
            }
            uint4 o0 = { pk_bf16(vals[0],  vals[1]),  pk_bf16(vals[2],  vals[3]),
                         pk_bf16(vals[4],  vals[5]),  pk_bf16(vals[6],  vals[7]) };
            uint4 o1 = { pk_bf16(vals[8],  vals[9]),  pk_bf16(vals[10], vals[11]),
                         pk_bf16(vals[12], vals[13]), pk_bf16(vals[14], vals[15]) };
            *(uint4*)(obase + c * 1024 +   0 + ln * 8) = o0;
            *(uint4*)(obase + c * 1024 + 512 + ln * 8) = o1;
        }
    }
}

// ---------------------------------------------------------------------------
// Main: 256 thr = 4 waves, 64 q-rows/block, grid 1024. blk%8 = qt%8 -> all 8
// heads of a (b,qt) share an XCD (bias-frag slice 2 MB/XCD, 8x reuse in L2).
// ZERO barriers. Per chunk: kf+bias frags prefetched ONE CHUNK AHEAD in regs
// (full-chunk load->use distance); vf issued at iter top, consumed at end.
// exp in C-layout with pre-masked bf16 bias; only DS traffic = wave-local P
// scatter (16 x b16, PSTR=72) + 2 x b128 read-back. Row sums via ones-MFMA.
// ---------------------------------------------------------------------------
__global__ __launch_bounds__(256, 4) void attn_fa2(
    const float* __restrict__ q,
    const float* __restrict__ v,
    const int*   __restrict__ mask,
    const unsigned short* __restrict__ kfrag,
    const unsigned short* __restrict__ vfrag,
    const unsigned short* __restrict__ bfrag,
    float*       __restrict__ out)
{
    __shared__ __align__(16) unsigned short sP[4][16 * PSTR];   // 9.2 KB

    const int tid  = threadIdx.x;
    const int wv   = tid >> 6;
    const int ln   = tid & 63;
    const int l16  = ln & 15;
    const int quad = ln >> 4;

    const int blk = blockIdx.x;
    const int h   = blk >> 7;
    const int rem = blk & 127;
    const int b   = rem >> 4;
    const int qt  = rem & 15;
    const int strip = qt * 4 + wv;
    const int q0  = strip * 16;
    const int bh  = b * H_ + h;

    const float scale = 0.17677669529663687f; // 1/sqrt(32), folded into Q

    bf16x8 qfrag;
    {
        const float* qp = q + ((size_t)(b * L_ + q0 + l16) * C_ + h * D_ + quad * 8);
        float4 a = ((const float4*)qp)[0];
        float4 c = ((const float4*)qp)[1];
        __align__(16) unsigned int u[4] = {
            pk_bf16(a.x * scale, a.y * scale), pk_bf16(a.z * scale, a.w * scale),
            pk_bf16(c.x * scale, c.y * scale), pk_bf16(c.z * scale, c.w * scale)};
        qfrag = *(const bf16x8*)u;
    }

    bf16x8 onesf;
#pragma unroll
    for (int i = 0; i < 8; ++i) onesf[i] = (short)0x3F80;

    const unsigned short* kf_base = kfrag + (size_t)bh * 32768 + ln * 8;
    const unsigned short* vf_base = vfrag + (size_t)bh * 32768 + ln * 8;
    const unsigned short* bm_base = bfrag + (size_t)(b * 64 + strip) * 16384 + ln * 8;
    unsigned short* const sPw = &sP[wv][0];

    f32x4 Oacc[2] = {{0.f,0.f,0.f,0.f},{0.f,0.f,0.f,0.f}};
    f32x4 Lacc    = {0.f,0.f,0.f,0.f};

    // ---- prologue: prefetch chunk 0's K-frags + bias-frags ----
    bf16x8 kf[4];
    uint4  bm[2];
#pragma unroll
    for (int nt = 0; nt < 4; ++nt)
        kf[nt] = *(const bf16x8*)(kf_base + nt * 512);
    bm[0] = *(const uint4*)(bm_base);
    bm[1] = *(const uint4*)(bm_base + 512);

    for (int c = 0; c < 16; ++c) {
        // ---- V-frags for this chunk: issued now, consumed ~400 cyc later ----
        bf16x8 vf[4];
#pragma unroll
        for (int u2 = 0; u2 < 4; ++u2)
            vf[u2] = *(const bf16x8*)(vf_base + c * 2048 + u2 * 512);

        // ---- QK^T on prefetched kf ----
        f32x4 S[4];
#pragma unroll
        for (int nt = 0; nt < 4; ++nt)
            S[nt] = __builtin_amdgcn_mfma_f32_16x16x32_bf16(
                qfrag, kf[nt], (f32x4){0.f,0.f,0.f,0.f}, 0, 0, 0);

        // ---- prefetch chunk c+1 (kf + bias) while we do exp/PV ----
        const int cn = (c < 15) ? c + 1 : 15;
        bf16x8 kfN[4];
        uint4  bmN[2];
#pragma unroll
        for (int nt = 0; nt < 4; ++nt)
            kfN[nt] = *(const bf16x8*)(kf_base + cn * 2048 + nt * 512);
        bmN[0] = *(const uint4*)(bm_base + cn * 1024);
        bmN[1] = *(const uint4*)(bm_base + cn * 1024 + 512);

        // ---- exp in C-layout with pre-masked bf16 bias; scatter P ----
        unsigned short* dst0 = sPw + quad * 4 * PSTR + l16;
#pragma unroll
        for (int nt = 0; nt < 4; ++nt) {
            const unsigned int w0 = ((const unsigned int*)&bm[nt >> 1])[(nt & 1) * 2 + 0];
            const unsigned int w1 = ((const unsigned int*)&bm[nt >> 1])[(nt & 1) * 2 + 1];
            const float b0 = __uint_as_float(w0 << 16);
            const float b1 = __uint_as_float(w0 & 0xffff0000u);
            const float b2 = __uint_as_float(w1 << 16);
            const float b3 = __uint_as_float(w1 & 0xffff0000u);
            const float p0 = __expf(S[nt][0] + b0);   // masked key: bias=-1e9 -> 0
            const float p1 = __expf(S[nt][1] + b1);
            const float p2 = __expf(S[nt][2] + b2);
            const float p3 = __expf(S[nt][3] + b3);
            const unsigned int plo = pk_bf16(p0, p1);
            const unsigned int phi = pk_bf16(p2, p3);
            unsigned short* d = dst0 + nt * 16;
            d[0 * PSTR] = (unsigned short)plo;
            d[1 * PSTR] = (unsigned short)(plo >> 16);
            d[2 * PSTR] = (unsigned short)phi;
            d[3 * PSTR] = (unsigned short)(phi >> 16);
        }

        // ---- P A-frags (wave-local, in-order DS) + PV + row-sum MFMA ----
#pragma unroll
        for (int s2 = 0; s2 < 2; ++s2) {
            bf16x8 pf = *(const bf16x8*)(sPw + l16 * PSTR + s2 * 32 + quad * 8);
            Lacc = __builtin_amdgcn_mfma_f32_16x16x32_bf16(pf, onesf, Lacc, 0, 0, 0);
            Oacc[0] = __builtin_amdgcn_mfma_f32_16x16x32_bf16(pf, vf[s2 * 2 + 0], Oacc[0], 0, 0, 0);
            Oacc[1] = __builtin_amdgcn_mfma_f32_16x16x32_bf16(pf, vf[s2 * 2 + 1], Oacc[1], 0, 0, 0);
        }

        // ---- rotate prefetch ----
#pragma unroll
        for (int nt = 0; nt < 4; ++nt) kf[nt] = kfN[nt];
        bm[0] = bmN[0];
        bm[1] = bmN[1];
    }

    // ---- epilogue: Lacc holds row sums; normalize or pass value through ----
#pragma unroll
    for (int r = 0; r < 4; ++r) {
        const int qrow = q0 + quad * 4 + r;
        const int active = mask[b * L_ + qrow];
        const float inv = 1.f / Lacc[r];
        const size_t base = (size_t)(b * L_ + qrow) * C_ + h * D_;
#pragma unroll
        for (int nt = 0; nt < 2; ++nt) {
            const size_t idx = base + nt * 16 + l16;
            out[idx] = active ? Oacc[nt][r] * inv : v[idx];
        }
    }
}

// ---------------------------------------------------------------------------
// Round-2 fallback if ws_size < 24 MB (proven correct, self-contained).
// ---------------------------------------------------------------------------
#define MQ    64
#define KSTR  48
#define VSTR  72

__global__ __launch_bounds__(256) void masked_attn_mfma(
    const float* __restrict__ q,
    const float* __restrict__ k,
    const float* __restrict__ v,
    const int*   __restrict__ mask,
    const float* __restrict__ bias,
    float*       __restrict__ out)
{
    __shared__ __align__(16) unsigned short sQ[MQ][KSTR];
    __shared__ __align__(16) unsigned short sKt[NK][KSTR];
    __shared__ __align__(16) unsigned short sVt[D_][VSTR];
    __shared__ __align__(16) unsigned short sP2[4][16][VSTR];
    __shared__ float sMadd2[NK];

    const int tid  = threadIdx.x;
    const int wv   = tid >> 6;
    const int ln   = tid & 63;
    const int l16  = ln & 15;
    const int quad = ln >> 4;

    const int blk = blockIdx.x;
    const int h   = blk & 7;
    const int qt  = (blk >> 3) & 15;
    const int b   = blk >> 7;
    const int q0  = qt * MQ;
    const float scale = 0.17677669529663687f;

    {
        const int row = tid >> 2, d0 = (tid & 3) * 8;
        const float* src = q + ((size_t)(b * L_ + q0 + row) * C_ + h * D_ + d0);
        float4 a = ((const float4*)src)[0];
        float4 c = ((const float4*)src)[1];
        __align__(16) unsigned short t8[8] = {
            f2bf(a.x), f2bf(a.y), f2bf(a.z), f2bf(a.w),
            f2bf(c.x), f2bf(c.y), f2bf(c.z), f2bf(c.w)};
        *(int4*)&sQ[row][d0] = *(const int4*)t8;
    }
    __syncthreads();

    const bf16x8 qfrag = *(const bf16x8*)&sQ[wv * 16 + l16][quad * 8];
    f32x4 Oacc[2] = {{0.f,0.f,0.f,0.f},{0.f,0.f,0.f,0.f}};
    float lsum[4] = {0.f, 0.f, 0.f, 0.f};

    for (int j0 = 0; j0 < L_; j0 += NK) {
        __syncthreads();
        {
            const int row = tid >> 2, d0 = (tid & 3) * 8;
            const size_t src = (size_t)(b * L_ + j0 + row) * C_ + h * D_ + d0;
            float4 ka = ((const float4*)(k + src))[0];
            float4 kb = ((const float4*)(k + src))[1];
            __align__(16) unsigned short t8[8] = {
                f2bf(ka.x), f2bf(ka.y), f2bf(ka.z), f2bf(ka.w),
                f2bf(kb.x), f2bf(kb.y), f2bf(kb.z), f2bf(kb.w)};
            *(int4*)&sKt[row][d0] = *(const int4*)t8;

            float4 va = ((const float4*)(v + src))[0];
            float4 vb = ((const float4*)(v + src))[1];
            sVt[d0 + 0][row] = f2bf(va.x);
            sVt[d0 + 1][row] = f2bf(va.y);
            sVt[d0 + 2][row] = f2bf(va.z);
            sVt[d0 + 3][row] = f2bf(va.w);
            sVt[d0 + 4][row] = f2bf(vb.x);
            sVt[d0 + 5][row] = f2bf(vb.y);
            sVt[d0 + 6][row] = f2bf(vb.z);
            sVt[d0 + 7][row] = f2bf(vb.w);
            if (tid < NK) sMadd2[tid] = mask[b * L_ + j0 + tid] ? 0.f : -1e9f;
        }
        __syncthreads();

        bf16x8 kf[4];
#pragma unroll
        for (int nt = 0; nt < 4; ++nt)
            kf[nt] = *(const bf16x8*)&sKt[nt * 16 + l16][quad * 8];

        f32x4 S[4];
#pragma unroll
        for (int nt = 0; nt < 4; ++nt)
            S[nt] = __builtin_amdgcn_mfma_f32_16x16x32_bf16(
                qfrag, kf[nt], (f32x4){0.f,0.f,0.f,0.f}, 0, 0, 0);

        float psum[4] = {0.f, 0.f, 0.f, 0.f};
        const size_t brow0 = (size_t)(b * L_ + q0 + wv * 16 + quad * 4) * L_ + j0;
#pragma unroll
        for (int nt = 0; nt < 4; ++nt) {
            const float madd = sMadd2[nt * 16 + l16];
#pragma unroll
            for (int r = 0; r < 4; ++r) {
                float s = S[nt][r] * scale + bias[brow0 + (size_t)r * L_ + nt * 16 + l16] + madd;
                float p = __expf(s);
                psum[r] += p;
                S[nt][r] = p;
            }
        }
#pragma unroll
        for (int nt = 0; nt < 4; ++nt)
#pragma unroll
            for (int r = 0; r < 4; ++r)
                sP2[wv][quad * 4 + r][nt * 16 + l16] = f2bf(S[nt][r]);
#pragma unroll
        for (int r = 0; r < 4; ++r) {
            float t = psum[r];
            t += __shfl_xor(t, 1);
            t += __shfl_xor(t, 2);
            t += __shfl_xor(t, 4);
            t += __shfl_xor(t, 8);
            lsum[r] += t;
        }
#pragma unroll
        for (int s2 = 0; s2 < 2; ++s2) {
            bf16x8 pf = *(const bf16x8*)&sP2[wv][l16][s2 * 32 + quad * 8];
#pragma unroll
            for (int nt = 0; nt < 2; ++nt) {
                bf16x8 vf = *(const bf16x8*)&sVt[nt * 16 + l16][s2 * 32 + quad * 8];
                Oacc[nt] = __builtin_amdgcn_mfma_f32_16x16x32_bf16(pf, vf, Oacc[nt], 0, 0, 0);
            }
        }
    }
#pragma unroll
    for (int r = 0; r < 4; ++r) {
        const int qg = q0 + wv * 16 + quad * 4 + r;
        const int active = mask[b * L_ + qg];
        const size_t obase = (size_t)(b * L_ + qg) * C_ + h * D_;
        const float inv = 1.f / lsum[r];
#pragma unroll
        for (int nt = 0; nt < 2; ++nt) {
            float val;
            if (active) val = Oacc[nt][r] * inv;
            else        val = v[obase + nt * 16 + l16];
            out[obase + nt * 16 + l16] = val;
        }
    }
}

extern "C" void kernel_launch(void* const* d_in, const int* in_sizes, int n_in,
                              void* d_out, int out_size, void* d_ws, size_t ws_size,
                              hipStream_t stream) {
    const float* q    = (const float*)d_in[0];
    const float* k    = (const float*)d_in[1];
    const float* v    = (const float*)d_in[2];
    const int*   mask = (const int*)d_in[3];
    const float* bias = (const float*)d_in[4];
    float* out = (float*)d_out;

    if (ws_size >= (size_t)24 * 1024 * 1024) {
        unsigned short* kfrag = (unsigned short*)d_ws;                 //  4 MB
        unsigned short* vfrag = kfrag + (size_t)2 * 1024 * 1024;       //  4 MB
        unsigned short* bfrag = vfrag + (size_t)2 * 1024 * 1024;       // 16 MB
        prep_all<<<1536, 256, 0, stream>>>(k, v, bias, mask, kfrag, vfrag, bfrag);
        attn_fa2<<<1024, 256, 0, stream>>>(q, v, mask, kfrag, vfrag, bfrag, out);
    } else {
        masked_attn_mfma<<<1024, 256, 0, stream>>>(q, k, v, mask, bias, out);
    }
}